// Round 16
// baseline (201.137 us; speedup 1.0000x reference)
//
#include <hip/hip_runtime.h>

#define DEV __device__ __forceinline__

typedef unsigned short u16;
typedef unsigned int u32;
using f32x4  = __attribute__((ext_vector_type(4))) float;
using f32x16 = __attribute__((ext_vector_type(16))) float;
using s16x8  = __attribute__((ext_vector_type(8))) short;
using u32x2  = __attribute__((ext_vector_type(2))) u32;
using u32x4  = __attribute__((ext_vector_type(4))) u32;
typedef int i32x2 __attribute__((ext_vector_type(2)));

#if __has_builtin(__builtin_amdgcn_exp2f)
#define EXP2(x) __builtin_amdgcn_exp2f(x)
#else
#define EXP2(x) exp2f(x)
#endif

#define WAITV(N) asm volatile("s_waitcnt vmcnt(" #N ")" ::: "memory")

__constant__ const float C2_SCALE = 0.18033688011112042f;  // 0.125 * log2(e)
#define S2_SHIFT 17.312340490667560f                       // 12 * log2(e)

// ---------- bf16 helpers ----------
DEV u16 f2b(float f) {
  union { float f; u32 u; } v; v.f = f;
  return (u16)((v.u + 0x7FFFu + ((v.u >> 16) & 1u)) >> 16);  // RNE
}
DEV float b2f(u16 u) {
  union { u32 u; float f; } v; v.u = ((u32)u) << 16;
  return v.f;
}

DEV u32 cvtpk(float lo, float hi) {
  u32 r;
  asm("v_cvt_pk_bf16_f32 %0, %1, %2" : "=v"(r) : "v"(lo), "v"(hi));
  return r;
}

// v_permlane32_swap: a.lanes[32:63] <-> b.lanes[0:31]
#if __has_builtin(__builtin_amdgcn_permlane32_swap)
DEV void lane32_swap(u32& x, u32& y) {
  i32x2 r = __builtin_amdgcn_permlane32_swap((int)x, (int)y, false, false);
  x = (u32)r[0]; y = (u32)r[1];
}
#else
DEV void lane32_swap(u32& x, u32& y) {
  u32 xo = (u32)__shfl_xor((int)x, 32, 64);
  u32 yo = (u32)__shfl_xor((int)y, 32, 64);
  int hi = (int)((threadIdx.x & 63) >> 5);
  u32 nx = hi ? yo : x;
  u32 ny = hi ? y : xo;
  x = nx; y = ny;
}
#endif

DEV void gload16(const void* g, void* l) {
  __builtin_amdgcn_global_load_lds(
      (const __attribute__((address_space(1))) void*)g,
      (__attribute__((address_space(3))) void*)l, 16, 0, 0);
}

// ---------- fp32 -> bf16 conversion ----------
__global__ __launch_bounds__(256) void k_cvt(const float* __restrict__ src,
                                             u16* __restrict__ dst, int n4) {
  int i = blockIdx.x * 256 + threadIdx.x;
  if (i >= n4) return;
  float4 v = ((const float4*)src)[i];
  ushort4 o;
  o.x = f2b(v.x); o.y = f2b(v.y); o.z = f2b(v.z); o.w = f2b(v.w);
  ((ushort4*)dst)[i] = o;
}

// fused 4-weight cvt: 4096 blocks = 1024 per weight (262144 float4 each).
__global__ __launch_bounds__(256) void k_cvt_w(
    const float* __restrict__ s0, const float* __restrict__ s1,
    const float* __restrict__ s2, const float* __restrict__ s3,
    u16* __restrict__ dst) {
  int blk = blockIdx.x;                      // 0..4095
  int widx = blk >> 10;                      // 0..3
  int i = (blk & 1023) * 256 + threadIdx.x;  // 0..262143 float4
  const float* src = widx == 0 ? s0 : widx == 1 ? s1 : widx == 2 ? s2 : s3;
  float4 v = ((const float4*)src)[i];
  ushort4 o;
  o.x = f2b(v.x); o.y = f2b(v.y); o.z = f2b(v.z); o.w = f2b(v.w);
  ((ushort4*)(dst + (size_t)widx * 1048576))[i] = o;
}

// ---------- 256x256 GEMM for the fused QK projection (minimal-sync) ----------
#define QUAD(QA, QB)                                                          \
  do {                                                                        \
    _Pragma("unroll")                                                         \
    for (int kk = 0; kk < 2; ++kk)                                            \
      _Pragma("unroll")                                                       \
      for (int f = 0; f < 4; ++f)                                             \
        _Pragma("unroll")                                                     \
        for (int j = 0; j < 2; ++j)                                           \
          acc[(QA)*4 + f][(QB)*2 + j] = __builtin_amdgcn_mfma_f32_16x16x32_bf16( \
              af[f][kk], bf[(QB)*2 + j][kk], acc[(QA)*4 + f][(QB)*2 + j], 0, 0, 0); \
  } while (0)

__global__ __launch_bounds__(512, 2) void k_gemm8(
    const u16* __restrict__ A, const u16* __restrict__ Bw,
    const float* __restrict__ bq, const float* __restrict__ bk,
    u16* __restrict__ C, int M, int N, int K) {
  __shared__ alignas(16) u16 lds_[65536];  // 128 KB: 2 bufs x (A 32K | B 32K)
  char* lds = (char*)lds_;
  const int t = threadIdx.x;
  const int wave = t >> 6, lane = t & 63;
  const int g = lane >> 4, fr = lane & 15;
  const int wm = wave >> 2, wn = wave & 3;  // 2 x 4 wave grid
  const int m0 = blockIdx.y * 256, n0 = blockIdx.x * 256;
  const int seg = t & 7, trow = t >> 3;

  auto stage_chunk = [&](int kt, int buf, int chunk) {
    const int k0 = kt << 6;
    const u16* src = (chunk < 2) ? A : Bw;
    const int isB = chunk >> 1, half = chunk & 1;
    const int gbase = (isB ? n0 : m0) + half * 128;
    char* dbase = lds + buf * 65536 + isB * 32768 + half * 16384 + wave * 1024;
#pragma unroll
    for (int r = 0; r < 2; ++r) {
      int rowc = r * 64 + trow;
      gload16(src + (size_t)(gbase + rowc) * K + k0 + 8 * (seg ^ (rowc & 7)),
              dbase + r * 8192);
    }
  };

  f32x4 acc[8][4];
#pragma unroll
  for (int i = 0; i < 8; ++i)
#pragma unroll
    for (int j = 0; j < 4; ++j)
#pragma unroll
      for (int r = 0; r < 4; ++r) acc[i][j][r] = 0.f;

  s16x8 af[4][2], bf[4][2];
  const int nk = K >> 6;  // 16

  stage_chunk(0, 0, 0); stage_chunk(0, 0, 1);
  stage_chunk(0, 0, 2); stage_chunk(0, 0, 3);

  for (int kt = 0; kt < nk; ++kt) {
    const int cur = kt & 1, nxt = cur ^ 1;
    const bool more = (kt + 1 < nk);
    const char* ab = lds + cur * 65536;
    const char* bb = lds + cur * 65536 + 32768;

    auto lda = [&](int f, int kk) -> s16x8 {
      int row = wm * 128 + f * 16 + fr;
      return *(const s16x8*)(ab + row * 128 + ((kk * 64 + g * 16) ^ ((row & 7) << 4)));
    };
    auto ldb = [&](int j, int kk) -> s16x8 {
      int row = wn * 64 + j * 16 + fr;
      return *(const s16x8*)(bb + row * 128 + ((kk * 64 + g * 16) ^ ((row & 7) << 4)));
    };

    if (more) {
      stage_chunk(kt + 1, nxt, 0); stage_chunk(kt + 1, nxt, 1);
      stage_chunk(kt + 1, nxt, 2); stage_chunk(kt + 1, nxt, 3);
      WAITV(8);
    } else {
      WAITV(0);
    }
    __builtin_amdgcn_s_barrier();
    __builtin_amdgcn_sched_barrier(0);

#pragma unroll
    for (int f = 0; f < 4; ++f) { af[f][0] = lda(f, 0); af[f][1] = lda(f, 1); }
#pragma unroll
    for (int j = 0; j < 2; ++j) { bf[j][0] = ldb(j, 0); bf[j][1] = ldb(j, 1); }
    __builtin_amdgcn_s_setprio(1); QUAD(0, 0); __builtin_amdgcn_s_setprio(0);
#pragma unroll
    for (int j = 2; j < 4; ++j) { bf[j][0] = ldb(j, 0); bf[j][1] = ldb(j, 1); }
    __builtin_amdgcn_s_setprio(1); QUAD(0, 1); __builtin_amdgcn_s_setprio(0);
#pragma unroll
    for (int f = 0; f < 4; ++f) { af[f][0] = lda(f + 4, 0); af[f][1] = lda(f + 4, 1); }
    __builtin_amdgcn_s_setprio(1); QUAD(1, 1); QUAD(1, 0); __builtin_amdgcn_s_setprio(0);

    __builtin_amdgcn_s_barrier();
  }

#pragma unroll
  for (int j = 0; j < 4; ++j) {
    const int coltile = n0 + wn * 64 + j * 16;
    const bool isK = coltile >= 1024;
    const float* bp = isK ? (bk - 1024) : bq;
    const float sc = isK ? C2_SCALE : 1.f;
#pragma unroll
    for (int f = 0; f < 8; ++f)
#pragma unroll
      for (int r = 0; r < 4; ++r) {
        int row = m0 + wm * 128 + f * 16 + g * 4 + r;
        int col = coltile + fr;
        C[(size_t)row * N + col] = f2b((acc[f][j][r] + bp[col]) * sc);
      }
  }
}

// ---------- NT GEMM (2-phase 128x128, proven): VT + O-proj ----------
template <int MODE>
__global__ __launch_bounds__(256) void k_gemm_bt(
    const u16* __restrict__ A, const u16* __restrict__ Bw,
    const float* __restrict__ bias0, u16* __restrict__ C,
    int M, int N, int K) {
  __shared__ alignas(16) u16 lds_[16384];  // 32 KB
  char* lds = (char*)lds_;
  const int t = threadIdx.x;
  const int wave = t >> 6, lane = t & 63;
  const int g = lane >> 4, fr = lane & 15;
  const int wr = (wave >> 1) * 64, wc = (wave & 1) * 64;
  const int m0 = blockIdx.y * 128, n0 = blockIdx.x * 128;
  const int chunk = t & 3;

  auto stage = [&](int k0, int buf) {
#pragma unroll
    for (int r = 0; r < 2; ++r) {
      int row = r * 64 + (t >> 2);
      int sw = 8 * (chunk ^ ((row >> 1) & 3));
      char* dst = lds + buf * 16384 + r * 4096 + wave * 1024;
      gload16(A  + (size_t)(m0 + row) * K + k0 + sw, dst);
      gload16(Bw + (size_t)(n0 + row) * K + k0 + sw, dst + 8192);
    }
  };

  f32x4 acc[4][4];
#pragma unroll
  for (int i = 0; i < 4; ++i)
#pragma unroll
    for (int j = 0; j < 4; ++j)
#pragma unroll
      for (int r = 0; r < 4; ++r) acc[i][j][r] = 0.f;

  const int nk = K >> 5;
  stage(0, 0);
  __syncthreads();
  for (int kt = 0; kt < nk; ++kt) {
    const int cur = kt & 1;
    if (kt + 1 < nk) stage((kt + 1) << 5, cur ^ 1);
    s16x8 af[4], bf4[4];
#pragma unroll
    for (int i = 0; i < 4; ++i) {
      int row = wr + i * 16 + fr;
      af[i] = *(const s16x8*)(lds + cur * 16384 + row * 64 +
                              ((g * 16) ^ ((((row >> 1) & 3)) << 4)));
    }
#pragma unroll
    for (int j = 0; j < 4; ++j) {
      int row = wc + j * 16 + fr;
      bf4[j] = *(const s16x8*)(lds + cur * 16384 + 8192 + row * 64 +
                               ((g * 16) ^ ((((row >> 1) & 3)) << 4)));
    }
    __builtin_amdgcn_s_setprio(1);
#pragma unroll
    for (int i = 0; i < 4; ++i)
#pragma unroll
      for (int j = 0; j < 4; ++j)
        acc[i][j] = __builtin_amdgcn_mfma_f32_16x16x32_bf16(af[i], bf4[j], acc[i][j], 0, 0, 0);
    __builtin_amdgcn_s_setprio(0);
    __syncthreads();
  }
#pragma unroll
  for (int j = 0; j < 4; ++j) {
#pragma unroll
    for (int i = 0; i < 4; ++i)
#pragma unroll
      for (int r = 0; r < 4; ++r) {
        int row = m0 + wr + i * 16 + g * 4 + r;
        int col = n0 + wc + j * 16 + fr;
        float v = acc[i][j][r] + (MODE == 1 ? bias0[row] : bias0[col]);
        C[(size_t)row * N + col] = f2b(v);
      }
  }
}

// ---------- flash attention: 4 waves, 64 q/wave, KVBLK=128 window ----------
// r14 base; within-window reorder only: QK tt-major, then pack/PV in ks-pairs
// so pack(ks2,3) VALU is independent of PV(ks0,1) MFMAs (scheduler interleaves).
// Per-accumulator op order identical to r14 -> bit-exact output expected.
__global__ __launch_bounds__(256, 2) void k_attn(
    const u16* __restrict__ qkb, const u16* __restrict__ vtb,
    u16* __restrict__ ctx) {
  __shared__ alignas(16) u16 smem_[32768];  // 64 KB: 2 bufs x (K 16K | V 16K)
  char* smem = (char*)smem_;
  const int bh = blockIdx.x;
  const int b = bh >> 4, h = bh & 15;
  const int qblk = blockIdx.y;
  const int t = threadIdx.x, w = t >> 6, lane = t & 63;
  const int l31 = lane & 31, hi = lane >> 5;
  const int hc = h * 64;
  const int q0 = qblk * 256 + w * 64;

  s16x8 qf[2][4];
#pragma unroll
  for (int s = 0; s < 2; ++s) {
    const u16* qrow = qkb + (size_t)(b * 2048 + q0 + s * 32 + l31) * 2048 + hc + hi * 8;
#pragma unroll
    for (int ks = 0; ks < 4; ++ks) qf[s][ks] = *(const s16x8*)(qrow + ks * 16);
  }

  const u16* kbase  = qkb + (size_t)(b * 2048) * 2048 + 1024 + hc;
  const u16* vtbase = vtb + (size_t)hc * 8192 + b * 2048;

  const int lrow = lane >> 3, seg = lane & 7;
  const int vr4 = lane >> 4, vs16 = lane & 15;
  auto stage = [&](int kt, int buf) {
    const int k0 = kt * 128;
#pragma unroll
    for (int r = 0; r < 4; ++r) {
      int row = w * 32 + r * 8 + lrow;
      gload16(kbase + (size_t)(k0 + row) * 2048 + 8 * (seg ^ (row & 7)),
              smem + buf * 32768 + w * 4096 + r * 1024);
    }
#pragma unroll
    for (int r = 0; r < 4; ++r) {
      int row = w * 16 + r * 4 + vr4;
      gload16(vtbase + (size_t)row * 8192 + k0 + 8 * (vs16 ^ (row & 7)),
              smem + buf * 32768 + 16384 + w * 4096 + r * 1024);
    }
  };

  f32x16 octx[2][2], lacc[2], ns2;
#pragma unroll
  for (int r = 0; r < 16; ++r) {
    octx[0][0][r] = 0.f; octx[0][1][r] = 0.f;
    octx[1][0][r] = 0.f; octx[1][1][r] = 0.f;
    lacc[0][r] = 0.f; lacc[1][r] = 0.f;
    ns2[r] = -S2_SHIFT;
  }
  s16x8 ones;
#pragma unroll
  for (int j = 0; j < 8; ++j) ones[j] = (short)0x3F80;  // bf16 1.0

  stage(0, 0);
  __syncthreads();
  for (int kt = 0; kt < 16; ++kt) {
    const int cur = kt & 1;
    if (kt + 1 < 16) stage(kt + 1, cur ^ 1);
    const char* kb_ = smem + cur * 32768;
    const char* vb_ = smem + cur * 32768 + 16384;

#pragma unroll
    for (int hh = 0; hh < 2; ++hh) {
      // ---- QK^T, tt-major (st[*][0] completes before st[*][1]) ----
      f32x16 st[2][2];
      __builtin_amdgcn_s_setprio(1);
#pragma unroll
      for (int tt = 0; tt < 2; ++tt)
#pragma unroll
        for (int ks = 0; ks < 4; ++ks) {
          int row = hh * 64 + tt * 32 + l31;
          s16x8 kf = *(const s16x8*)(kb_ + row * 128 +
                                     ((ks * 32 + hi * 16) ^ ((row & 7) << 4)));
#pragma unroll
          for (int s = 0; s < 2; ++s)
            st[s][tt] = __builtin_amdgcn_mfma_f32_32x32x16_bf16(
                kf, qf[s][ks], ks == 0 ? ns2 : st[s][tt], 0, 0, 0);
        }
      __builtin_amdgcn_s_setprio(0);

      s16x8 pf[2][4];
      // ---- pack ks 0,1 (uses st[*][0] only) ----
#pragma unroll
      for (int s = 0; s < 2; ++s)
#pragma unroll
        for (int ks = 0; ks < 2; ++ks) {
          const int base = (ks & 1) * 8;
          float e[8];
#pragma unroll
          for (int j = 0; j < 8; ++j) e[j] = EXP2(st[s][0][base + j]);
          u32 u0 = cvtpk(e[0], e[1]), u1 = cvtpk(e[2], e[3]);
          u32 v0 = cvtpk(e[4], e[5]), v1 = cvtpk(e[6], e[7]);
          lane32_swap(u0, v0);
          lane32_swap(u1, v1);
          u32x4 f; f[0] = u0; f[1] = u1; f[2] = v0; f[3] = v1;
          pf[s][ks] = __builtin_bit_cast(s16x8, f);
        }
      // ---- PV ks 0,1 + lacc (MFMA; independent of pack ks 2,3 below) ----
      __builtin_amdgcn_s_setprio(1);
#pragma unroll
      for (int dt = 0; dt < 2; ++dt)
#pragma unroll
        for (int ks = 0; ks < 2; ++ks) {
          int row = dt * 32 + l31;
          s16x8 vf = *(const s16x8*)(vb_ + row * 256 +
                                     ((hh * 128 + ks * 32 + hi * 16) ^ ((row & 7) << 4)));
          octx[0][dt] = __builtin_amdgcn_mfma_f32_32x32x16_bf16(vf, pf[0][ks], octx[0][dt], 0, 0, 0);
          octx[1][dt] = __builtin_amdgcn_mfma_f32_32x32x16_bf16(vf, pf[1][ks], octx[1][dt], 0, 0, 0);
        }
#pragma unroll
      for (int s = 0; s < 2; ++s)
#pragma unroll
        for (int ks = 0; ks < 2; ++ks)
          lacc[s] = __builtin_amdgcn_mfma_f32_32x32x16_bf16(ones, pf[s][ks], lacc[s], 0, 0, 0);
      __builtin_amdgcn_s_setprio(0);

      // ---- pack ks 2,3 (uses st[*][1] only) ----
#pragma unroll
      for (int s = 0; s < 2; ++s)
#pragma unroll
        for (int ks = 2; ks < 4; ++ks) {
          const int base = (ks & 1) * 8;
          float e[8];
#pragma unroll
          for (int j = 0; j < 8; ++j) e[j] = EXP2(st[s][1][base + j]);
          u32 u0 = cvtpk(e[0], e[1]), u1 = cvtpk(e[2], e[3]);
          u32 v0 = cvtpk(e[4], e[5]), v1 = cvtpk(e[6], e[7]);
          lane32_swap(u0, v0);
          lane32_swap(u1, v1);
          u32x4 f; f[0] = u0; f[1] = u1; f[2] = v0; f[3] = v1;
          pf[s][ks] = __builtin_bit_cast(s16x8, f);
        }
      // ---- PV ks 2,3 + lacc ----
      __builtin_amdgcn_s_setprio(1);
#pragma unroll
      for (int dt = 0; dt < 2; ++dt)
#pragma unroll
        for (int ks = 2; ks < 4; ++ks) {
          int row = dt * 32 + l31;
          s16x8 vf = *(const s16x8*)(vb_ + row * 256 +
                                     ((hh * 128 + ks * 32 + hi * 16) ^ ((row & 7) << 4)));
          octx[0][dt] = __builtin_amdgcn_mfma_f32_32x32x16_bf16(vf, pf[0][ks], octx[0][dt], 0, 0, 0);
          octx[1][dt] = __builtin_amdgcn_mfma_f32_32x32x16_bf16(vf, pf[1][ks], octx[1][dt], 0, 0, 0);
        }
#pragma unroll
      for (int s = 0; s < 2; ++s)
#pragma unroll
        for (int ks = 2; ks < 4; ++ks)
          lacc[s] = __builtin_amdgcn_mfma_f32_32x32x16_bf16(ones, pf[s][ks], lacc[s], 0, 0, 0);
      __builtin_amdgcn_s_setprio(0);
    }
    __syncthreads();
  }

  float linv[2];
#pragma unroll
  for (int s = 0; s < 2; ++s) linv[s] = 1.0f / lacc[s][0];

  // ---- ctx^T frags -> LDS (packed b64), then coalesced store; 256 rows x 128B ----
#pragma unroll
  for (int s = 0; s < 2; ++s) {
    const int ql = w * 64 + s * 32 + l31;
#pragma unroll
    for (int dt = 0; dt < 2; ++dt)
#pragma unroll
      for (int rq = 0; rq < 4; ++rq) {
        int d0 = 8 * rq + 4 * hi + 32 * dt;
        u32x2 pk;
        pk[0] = cvtpk(octx[s][dt][4 * rq + 0] * linv[s], octx[s][dt][4 * rq + 1] * linv[s]);
        pk[1] = cvtpk(octx[s][dt][4 * rq + 2] * linv[s], octx[s][dt][4 * rq + 3] * linv[s]);
        *(u32x2*)(smem + ql * 128 + ((2 * d0) ^ ((ql & 7) << 4))) = pk;
      }
  }
  __syncthreads();
  {
    int qr = t;
    u16* dst = ctx + (size_t)(b * 2048 + qblk * 256 + qr) * 1024 + hc;
#pragma unroll
    for (int i = 0; i < 8; ++i) {
      s16x8 v = *(const s16x8*)(smem + qr * 128 + ((i * 16) ^ ((qr & 7) << 4)));
      *(s16x8*)(dst + i * 8) = v;
    }
  }
}

// ---------- conv1d + residual + LayerNorm epilogue (XCD-chunked remap) ----------
__global__ __launch_bounds__(256) void k_epi(
    const float* __restrict__ x, const u16* __restrict__ gab,
    const float* __restrict__ cw, const float* __restrict__ cb,
    const float* __restrict__ lg, const float* __restrict__ lb,
    float* __restrict__ out) {
  __shared__ float red[4];
  const int n = ((blockIdx.x & 7) << 10) | (blockIdx.x >> 3);  // bijective, 8192 blocks
  const int s = n & 2047;
  const int t = threadIdx.x;
  const int d0 = t * 4;
  const float* xr = x + (size_t)n * 1024;

  float xc[4], xm[4], xp[4];
  { float4 v = *(const float4*)(xr + d0); xc[0]=v.x; xc[1]=v.y; xc[2]=v.z; xc[3]=v.w; }
  if (s > 0) { float4 v = *(const float4*)(xr - 1024 + d0); xm[0]=v.x; xm[1]=v.y; xm[2]=v.z; xm[3]=v.w; }
  else { xm[0]=xm[1]=xm[2]=xm[3]=0.f; }
  if (s < 2047) { float4 v = *(const float4*)(xr + 1024 + d0); xp[0]=v.x; xp[1]=v.y; xp[2]=v.z; xp[3]=v.w; }
  else { xp[0]=xp[1]=xp[2]=xp[3]=0.f; }
  ushort4 gv = *(const ushort4*)(gab + (size_t)n * 1024 + d0);
  float ga4[4] = { b2f(gv.x), b2f(gv.y), b2f(gv.z), b2f(gv.w) };

  float y[4];
#pragma unroll
  for (int i = 0; i < 4; ++i) {
    int d = d0 + i;
    float lo = xm[i] * cw[d * 3] + xc[i] * cw[d * 3 + 1] + xp[i] * cw[d * 3 + 2] + cb[d];
    y[i] = xc[i] + ga4[i] + 0.3f * lo;
  }

  float sm = y[0] + y[1] + y[2] + y[3];
#pragma unroll
  for (int off = 32; off >= 1; off >>= 1) sm += __shfl_xor(sm, off, 64);
  if ((t & 63) == 0) red[t >> 6] = sm;
  __syncthreads();
  float mu = (red[0] + red[1] + red[2] + red[3]) * (1.f / 1024.f);
  __syncthreads();

  float vs = 0.f;
#pragma unroll
  for (int i = 0; i < 4; ++i) { float dd = y[i] - mu; vs += dd * dd; }
#pragma unroll
  for (int off = 32; off >= 1; off >>= 1) vs += __shfl_xor(vs, off, 64);
  if ((t & 63) == 0) red[t >> 6] = vs;
  __syncthreads();
  float var = (red[0] + red[1] + red[2] + red[3]) * (1.f / 1024.f);
  float rs = rsqrtf(var + 1e-5f);
#pragma unroll
  for (int i = 0; i < 4; ++i) {
    int d = d0 + i;
    out[(size_t)n * 1024 + d] = (y[i] - mu) * rs * lg[d] + lb[d];
  }
}

// ---------- launch ----------
extern "C" void kernel_launch(void* const* d_in, const int* in_sizes, int n_in,
                              void* d_out, int out_size, void* d_ws, size_t ws_size,
                              hipStream_t stream) {
  const float* x  = (const float*)d_in[0];
  const float* wq = (const float*)d_in[1];
  const float* bq = (const float*)d_in[2];
  const float* wk = (const float*)d_in[3];
  const float* bk = (const float*)d_in[4];
  const float* wv = (const float*)d_in[5];
  const float* bv = (const float*)d_in[6];
  const float* wo = (const float*)d_in[7];
  const float* bo = (const float*)d_in[8];
  const float* cw = (const float*)d_in[9];
  const float* cb = (const float*)d_in[10];
  const float* lg = (const float*)d_in[11];
  const float* lb = (const float*)d_in[12];
  float* out = (float*)d_out;

  char* ws = (char*)d_ws;
  const size_t MB = 1ull << 20;
  u16* xb  = (u16*)(ws + 0);        // 16MB; reused as ctx
  u16* wqb = (u16*)(ws + 16 * MB);  // wq|wk|wv|wo contiguous, 8MB
  u16* wvb = (u16*)(ws + 20 * MB);
  u16* wob = (u16*)(ws + 22 * MB);
  u16* qkb = (u16*)(ws + 24 * MB);  // 32MB [8192][2048]; reused as global_attn
  u16* vtb = (u16*)(ws + 56 * MB);  // 16MB V^T [1024 d][8192 tok]
  u16* ctx = xb;
  u16* gab = qkb;

  k_cvt<<<8192, 256, 0, stream>>>(x, xb, 2097152);
  k_cvt_w<<<4096, 256, 0, stream>>>(wq, wk, wv, wo, wqb);

  // fused [Q | K*c2] = X [wq|wk]^T : [8192][2048]
  k_gemm8<<<dim3(8, 32), 512, 0, stream>>>(xb, wqb, bq, bk, qkb, 8192, 2048, 1024);
  // V^T = Wv X^T (row-bias): [1024][8192]
  k_gemm_bt<1><<<dim3(64, 8), 256, 0, stream>>>(wvb, xb, bv, vtb, 1024, 8192, 1024);

  k_attn<<<dim3(64, 8), 256, 0, stream>>>(qkb, vtb, ctx);

  k_gemm_bt<0><<<dim3(8, 64), 256, 0, stream>>>(ctx, wob, bo, gab, 8192, 1024, 1024);

  k_epi<<<8192, 256, 0, stream>>>(x, gab, cw, cb, lg, lb, out);
}

// Round 17
// 198.212 us; speedup vs baseline: 1.0148x; 1.0148x over previous
//
#include <hip/hip_runtime.h>

#define DEV __device__ __forceinline__

typedef unsigned short u16;
typedef unsigned int u32;
using f32x4  = __attribute__((ext_vector_type(4))) float;
using f32x16 = __attribute__((ext_vector_type(16))) float;
using s16x8  = __attribute__((ext_vector_type(8))) short;
using u32x2  = __attribute__((ext_vector_type(2))) u32;
using u32x4  = __attribute__((ext_vector_type(4))) u32;
typedef int i32x2 __attribute__((ext_vector_type(2)));

#if __has_builtin(__builtin_amdgcn_exp2f)
#define EXP2(x) __builtin_amdgcn_exp2f(x)
#else
#define EXP2(x) exp2f(x)
#endif

#define WAITV(N) asm volatile("s_waitcnt vmcnt(" #N ")" ::: "memory")

__constant__ const float C2_SCALE = 0.18033688011112042f;  // 0.125 * log2(e)
#define S2_SHIFT 17.312340490667560f                       // 12 * log2(e)

// ---------- bf16 helpers ----------
DEV u16 f2b(float f) {
  union { float f; u32 u; } v; v.f = f;
  return (u16)((v.u + 0x7FFFu + ((v.u >> 16) & 1u)) >> 16);  // RNE
}
DEV float b2f(u16 u) {
  union { u32 u; float f; } v; v.u = ((u32)u) << 16;
  return v.f;
}

DEV u32 cvtpk(float lo, float hi) {
  u32 r;
  asm("v_cvt_pk_bf16_f32 %0, %1, %2" : "=v"(r) : "v"(lo), "v"(hi));
  return r;
}

// v_permlane32_swap: a.lanes[32:63] <-> b.lanes[0:31]
#if __has_builtin(__builtin_amdgcn_permlane32_swap)
DEV void lane32_swap(u32& x, u32& y) {
  i32x2 r = __builtin_amdgcn_permlane32_swap((int)x, (int)y, false, false);
  x = (u32)r[0]; y = (u32)r[1];
}
#else
DEV void lane32_swap(u32& x, u32& y) {
  u32 xo = (u32)__shfl_xor((int)x, 32, 64);
  u32 yo = (u32)__shfl_xor((int)y, 32, 64);
  int hi = (int)((threadIdx.x & 63) >> 5);
  u32 nx = hi ? yo : x;
  u32 ny = hi ? y : xo;
  x = nx; y = ny;
}
#endif

DEV void gload16(const void* g, void* l) {
  __builtin_amdgcn_global_load_lds(
      (const __attribute__((address_space(1))) void*)g,
      (__attribute__((address_space(3))) void*)l, 16, 0, 0);
}

// ---------- fused fp32 -> bf16 conversion: x (8192 blocks) + 4 weights ----------
__global__ __launch_bounds__(256) void k_cvt_all(
    const float* __restrict__ x, const float* __restrict__ s0,
    const float* __restrict__ s1, const float* __restrict__ s2,
    const float* __restrict__ s3, u16* __restrict__ xdst,
    u16* __restrict__ wdst) {
  int blk = blockIdx.x;  // 0..12287
  const float* src;
  u16* dst;
  int i;
  if (blk < 8192) {
    src = x; dst = xdst; i = blk * 256 + threadIdx.x;
  } else {
    int wb = blk - 8192;          // 0..4095
    int widx = wb >> 10;          // 0..3
    src = widx == 0 ? s0 : widx == 1 ? s1 : widx == 2 ? s2 : s3;
    dst = wdst + (size_t)widx * 1048576;
    i = (wb & 1023) * 256 + threadIdx.x;
  }
  float4 v = ((const float4*)src)[i];
  ushort4 o;
  o.x = f2b(v.x); o.y = f2b(v.y); o.z = f2b(v.z); o.w = f2b(v.w);
  ((ushort4*)dst)[i] = o;
}

// ---------- 256x256 GEMM for the fused QK projection (minimal-sync) ----------
#define QUAD(QA, QB)                                                          \
  do {                                                                        \
    _Pragma("unroll")                                                         \
    for (int kk = 0; kk < 2; ++kk)                                            \
      _Pragma("unroll")                                                       \
      for (int f = 0; f < 4; ++f)                                             \
        _Pragma("unroll")                                                     \
        for (int j = 0; j < 2; ++j)                                           \
          acc[(QA)*4 + f][(QB)*2 + j] = __builtin_amdgcn_mfma_f32_16x16x32_bf16( \
              af[f][kk], bf[(QB)*2 + j][kk], acc[(QA)*4 + f][(QB)*2 + j], 0, 0, 0); \
  } while (0)

__global__ __launch_bounds__(512, 2) void k_gemm8(
    const u16* __restrict__ A, const u16* __restrict__ Bw,
    const float* __restrict__ bq, const float* __restrict__ bk,
    u16* __restrict__ C, int M, int N, int K) {
  __shared__ alignas(16) u16 lds_[65536];  // 128 KB: 2 bufs x (A 32K | B 32K)
  char* lds = (char*)lds_;
  const int t = threadIdx.x;
  const int wave = t >> 6, lane = t & 63;
  const int g = lane >> 4, fr = lane & 15;
  const int wm = wave >> 2, wn = wave & 3;  // 2 x 4 wave grid
  const int m0 = blockIdx.y * 256, n0 = blockIdx.x * 256;
  const int seg = t & 7, trow = t >> 3;

  auto stage_chunk = [&](int kt, int buf, int chunk) {
    const int k0 = kt << 6;
    const u16* src = (chunk < 2) ? A : Bw;
    const int isB = chunk >> 1, half = chunk & 1;
    const int gbase = (isB ? n0 : m0) + half * 128;
    char* dbase = lds + buf * 65536 + isB * 32768 + half * 16384 + wave * 1024;
#pragma unroll
    for (int r = 0; r < 2; ++r) {
      int rowc = r * 64 + trow;
      gload16(src + (size_t)(gbase + rowc) * K + k0 + 8 * (seg ^ (rowc & 7)),
              dbase + r * 8192);
    }
  };

  f32x4 acc[8][4];
#pragma unroll
  for (int i = 0; i < 8; ++i)
#pragma unroll
    for (int j = 0; j < 4; ++j)
#pragma unroll
      for (int r = 0; r < 4; ++r) acc[i][j][r] = 0.f;

  s16x8 af[4][2], bf[4][2];
  const int nk = K >> 6;  // 16

  stage_chunk(0, 0, 0); stage_chunk(0, 0, 1);
  stage_chunk(0, 0, 2); stage_chunk(0, 0, 3);

  for (int kt = 0; kt < nk; ++kt) {
    const int cur = kt & 1, nxt = cur ^ 1;
    const bool more = (kt + 1 < nk);
    const char* ab = lds + cur * 65536;
    const char* bb = lds + cur * 65536 + 32768;

    auto lda = [&](int f, int kk) -> s16x8 {
      int row = wm * 128 + f * 16 + fr;
      return *(const s16x8*)(ab + row * 128 + ((kk * 64 + g * 16) ^ ((row & 7) << 4)));
    };
    auto ldb = [&](int j, int kk) -> s16x8 {
      int row = wn * 64 + j * 16 + fr;
      return *(const s16x8*)(bb + row * 128 + ((kk * 64 + g * 16) ^ ((row & 7) << 4)));
    };

    if (more) {
      stage_chunk(kt + 1, nxt, 0); stage_chunk(kt + 1, nxt, 1);
      stage_chunk(kt + 1, nxt, 2); stage_chunk(kt + 1, nxt, 3);
      WAITV(8);
    } else {
      WAITV(0);
    }
    __builtin_amdgcn_s_barrier();
    __builtin_amdgcn_sched_barrier(0);

#pragma unroll
    for (int f = 0; f < 4; ++f) { af[f][0] = lda(f, 0); af[f][1] = lda(f, 1); }
#pragma unroll
    for (int j = 0; j < 2; ++j) { bf[j][0] = ldb(j, 0); bf[j][1] = ldb(j, 1); }
    __builtin_amdgcn_s_setprio(1); QUAD(0, 0); __builtin_amdgcn_s_setprio(0);
#pragma unroll
    for (int j = 2; j < 4; ++j) { bf[j][0] = ldb(j, 0); bf[j][1] = ldb(j, 1); }
    __builtin_amdgcn_s_setprio(1); QUAD(0, 1); __builtin_amdgcn_s_setprio(0);
#pragma unroll
    for (int f = 0; f < 4; ++f) { af[f][0] = lda(f + 4, 0); af[f][1] = lda(f + 4, 1); }
    __builtin_amdgcn_s_setprio(1); QUAD(1, 1); QUAD(1, 0); __builtin_amdgcn_s_setprio(0);

    __builtin_amdgcn_s_barrier();
  }

#pragma unroll
  for (int j = 0; j < 4; ++j) {
    const int coltile = n0 + wn * 64 + j * 16;
    const bool isK = coltile >= 1024;
    const float* bp = isK ? (bk - 1024) : bq;
    const float sc = isK ? C2_SCALE : 1.f;
#pragma unroll
    for (int f = 0; f < 8; ++f)
#pragma unroll
      for (int r = 0; r < 4; ++r) {
        int row = m0 + wm * 128 + f * 16 + g * 4 + r;
        int col = coltile + fr;
        C[(size_t)row * N + col] = f2b((acc[f][j][r] + bp[col]) * sc);
      }
  }
}

// ---------- NT GEMM (2-phase 128x128, proven): VT + O-proj ----------
template <int MODE>
__global__ __launch_bounds__(256) void k_gemm_bt(
    const u16* __restrict__ A, const u16* __restrict__ Bw,
    const float* __restrict__ bias0, u16* __restrict__ C,
    int M, int N, int K) {
  __shared__ alignas(16) u16 lds_[16384];  // 32 KB
  char* lds = (char*)lds_;
  const int t = threadIdx.x;
  const int wave = t >> 6, lane = t & 63;
  const int g = lane >> 4, fr = lane & 15;
  const int wr = (wave >> 1) * 64, wc = (wave & 1) * 64;
  const int m0 = blockIdx.y * 128, n0 = blockIdx.x * 128;
  const int chunk = t & 3;

  auto stage = [&](int k0, int buf) {
#pragma unroll
    for (int r = 0; r < 2; ++r) {
      int row = r * 64 + (t >> 2);
      int sw = 8 * (chunk ^ ((row >> 1) & 3));
      char* dst = lds + buf * 16384 + r * 4096 + wave * 1024;
      gload16(A  + (size_t)(m0 + row) * K + k0 + sw, dst);
      gload16(Bw + (size_t)(n0 + row) * K + k0 + sw, dst + 8192);
    }
  };

  f32x4 acc[4][4];
#pragma unroll
  for (int i = 0; i < 4; ++i)
#pragma unroll
    for (int j = 0; j < 4; ++j)
#pragma unroll
      for (int r = 0; r < 4; ++r) acc[i][j][r] = 0.f;

  const int nk = K >> 5;
  stage(0, 0);
  __syncthreads();
  for (int kt = 0; kt < nk; ++kt) {
    const int cur = kt & 1;
    if (kt + 1 < nk) stage((kt + 1) << 5, cur ^ 1);
    s16x8 af[4], bf4[4];
#pragma unroll
    for (int i = 0; i < 4; ++i) {
      int row = wr + i * 16 + fr;
      af[i] = *(const s16x8*)(lds + cur * 16384 + row * 64 +
                              ((g * 16) ^ ((((row >> 1) & 3)) << 4)));
    }
#pragma unroll
    for (int j = 0; j < 4; ++j) {
      int row = wc + j * 16 + fr;
      bf4[j] = *(const s16x8*)(lds + cur * 16384 + 8192 + row * 64 +
                               ((g * 16) ^ ((((row >> 1) & 3)) << 4)));
    }
    __builtin_amdgcn_s_setprio(1);
#pragma unroll
    for (int i = 0; i < 4; ++i)
#pragma unroll
      for (int j = 0; j < 4; ++j)
        acc[i][j] = __builtin_amdgcn_mfma_f32_16x16x32_bf16(af[i], bf4[j], acc[i][j], 0, 0, 0);
    __builtin_amdgcn_s_setprio(0);
    __syncthreads();
  }
#pragma unroll
  for (int j = 0; j < 4; ++j) {
#pragma unroll
    for (int i = 0; i < 4; ++i)
#pragma unroll
      for (int r = 0; r < 4; ++r) {
        int row = m0 + wr + i * 16 + g * 4 + r;
        int col = n0 + wc + j * 16 + fr;
        float v = acc[i][j][r] + (MODE == 1 ? bias0[row] : bias0[col]);
        C[(size_t)row * N + col] = f2b(v);
      }
  }
}

// ---------- flash attention: 4 waves, 64 q/wave, KVBLK=128 window (r14 best) ----------
__global__ __launch_bounds__(256, 2) void k_attn(
    const u16* __restrict__ qkb, const u16* __restrict__ vtb,
    u16* __restrict__ ctx) {
  __shared__ alignas(16) u16 smem_[32768];  // 64 KB: 2 bufs x (K 16K | V 16K)
  char* smem = (char*)smem_;
  const int bh = blockIdx.x;
  const int b = bh >> 4, h = bh & 15;
  const int qblk = blockIdx.y;
  const int t = threadIdx.x, w = t >> 6, lane = t & 63;
  const int l31 = lane & 31, hi = lane >> 5;
  const int hc = h * 64;
  const int q0 = qblk * 256 + w * 64;

  s16x8 qf[2][4];
#pragma unroll
  for (int s = 0; s < 2; ++s) {
    const u16* qrow = qkb + (size_t)(b * 2048 + q0 + s * 32 + l31) * 2048 + hc + hi * 8;
#pragma unroll
    for (int ks = 0; ks < 4; ++ks) qf[s][ks] = *(const s16x8*)(qrow + ks * 16);
  }

  const u16* kbase  = qkb + (size_t)(b * 2048) * 2048 + 1024 + hc;
  const u16* vtbase = vtb + (size_t)hc * 8192 + b * 2048;

  const int lrow = lane >> 3, seg = lane & 7;
  const int vr4 = lane >> 4, vs16 = lane & 15;
  auto stage = [&](int kt, int buf) {
    const int k0 = kt * 128;
#pragma unroll
    for (int r = 0; r < 4; ++r) {
      int row = w * 32 + r * 8 + lrow;
      gload16(kbase + (size_t)(k0 + row) * 2048 + 8 * (seg ^ (row & 7)),
              smem + buf * 32768 + w * 4096 + r * 1024);
    }
#pragma unroll
    for (int r = 0; r < 4; ++r) {
      int row = w * 16 + r * 4 + vr4;
      gload16(vtbase + (size_t)row * 8192 + k0 + 8 * (vs16 ^ (row & 7)),
              smem + buf * 32768 + 16384 + w * 4096 + r * 1024);
    }
  };

  f32x16 octx[2][2], lacc[2], ns2;
#pragma unroll
  for (int r = 0; r < 16; ++r) {
    octx[0][0][r] = 0.f; octx[0][1][r] = 0.f;
    octx[1][0][r] = 0.f; octx[1][1][r] = 0.f;
    lacc[0][r] = 0.f; lacc[1][r] = 0.f;
    ns2[r] = -S2_SHIFT;
  }
  s16x8 ones;
#pragma unroll
  for (int j = 0; j < 8; ++j) ones[j] = (short)0x3F80;  // bf16 1.0

  stage(0, 0);
  __syncthreads();
  for (int kt = 0; kt < 16; ++kt) {
    const int cur = kt & 1;
    if (kt + 1 < 16) stage(kt + 1, cur ^ 1);
    const char* kb_ = smem + cur * 32768;
    const char* vb_ = smem + cur * 32768 + 16384;

#pragma unroll
    for (int hh = 0; hh < 2; ++hh) {
      f32x16 st[2][2];
      __builtin_amdgcn_s_setprio(1);
#pragma unroll
      for (int ks = 0; ks < 4; ++ks) {
#pragma unroll
        for (int tt = 0; tt < 2; ++tt) {
          int row = hh * 64 + tt * 32 + l31;
          s16x8 kf = *(const s16x8*)(kb_ + row * 128 +
                                     ((ks * 32 + hi * 16) ^ ((row & 7) << 4)));
#pragma unroll
          for (int s = 0; s < 2; ++s)
            st[s][tt] = __builtin_amdgcn_mfma_f32_32x32x16_bf16(
                kf, qf[s][ks], ks == 0 ? ns2 : st[s][tt], 0, 0, 0);
        }
      }
      __builtin_amdgcn_s_setprio(0);

      s16x8 pf[2][4];
#pragma unroll
      for (int s = 0; s < 2; ++s) {
#pragma unroll
        for (int ks = 0; ks < 4; ++ks) {
          const int tt = ks >> 1, base = (ks & 1) * 8;
          float e[8];
#pragma unroll
          for (int j = 0; j < 8; ++j) e[j] = EXP2(st[s][tt][base + j]);
          u32 u0 = cvtpk(e[0], e[1]), u1 = cvtpk(e[2], e[3]);
          u32 v0 = cvtpk(e[4], e[5]), v1 = cvtpk(e[6], e[7]);
          lane32_swap(u0, v0);
          lane32_swap(u1, v1);
          u32x4 f; f[0] = u0; f[1] = u1; f[2] = v0; f[3] = v1;
          pf[s][ks] = __builtin_bit_cast(s16x8, f);
        }
      }

      __builtin_amdgcn_s_setprio(1);
#pragma unroll
      for (int dt = 0; dt < 2; ++dt)
#pragma unroll
        for (int ks = 0; ks < 4; ++ks) {
          int row = dt * 32 + l31;
          s16x8 vf = *(const s16x8*)(vb_ + row * 256 +
                                     ((hh * 128 + ks * 32 + hi * 16) ^ ((row & 7) << 4)));
          octx[0][dt] = __builtin_amdgcn_mfma_f32_32x32x16_bf16(vf, pf[0][ks], octx[0][dt], 0, 0, 0);
          octx[1][dt] = __builtin_amdgcn_mfma_f32_32x32x16_bf16(vf, pf[1][ks], octx[1][dt], 0, 0, 0);
        }
#pragma unroll
      for (int s = 0; s < 2; ++s)
#pragma unroll
        for (int ks = 0; ks < 4; ++ks)
          lacc[s] = __builtin_amdgcn_mfma_f32_32x32x16_bf16(ones, pf[s][ks], lacc[s], 0, 0, 0);
      __builtin_amdgcn_s_setprio(0);
    }
    __syncthreads();
  }

  float linv[2];
#pragma unroll
  for (int s = 0; s < 2; ++s) linv[s] = 1.0f / lacc[s][0];

#pragma unroll
  for (int s = 0; s < 2; ++s) {
    const int ql = w * 64 + s * 32 + l31;
#pragma unroll
    for (int dt = 0; dt < 2; ++dt)
#pragma unroll
      for (int rq = 0; rq < 4; ++rq) {
        int d0 = 8 * rq + 4 * hi + 32 * dt;
        u32x2 pk;
        pk[0] = cvtpk(octx[s][dt][4 * rq + 0] * linv[s], octx[s][dt][4 * rq + 1] * linv[s]);
        pk[1] = cvtpk(octx[s][dt][4 * rq + 2] * linv[s], octx[s][dt][4 * rq + 3] * linv[s]);
        *(u32x2*)(smem + ql * 128 + ((2 * d0) ^ ((ql & 7) << 4))) = pk;
      }
  }
  __syncthreads();
  {
    int qr = t;
    u16* dst = ctx + (size_t)(b * 2048 + qblk * 256 + qr) * 1024 + hc;
#pragma unroll
    for (int i = 0; i < 8; ++i) {
      s16x8 v = *(const s16x8*)(smem + qr * 128 + ((i * 16) ^ ((qr & 7) << 4)));
      *(s16x8*)(dst + i * 8) = v;
    }
  }
}

// ---------- conv1d + residual + LayerNorm epilogue (XCD-chunked remap) ----------
__global__ __launch_bounds__(256) void k_epi(
    const float* __restrict__ x, const u16* __restrict__ gab,
    const float* __restrict__ cw, const float* __restrict__ cb,
    const float* __restrict__ lg, const float* __restrict__ lb,
    float* __restrict__ out) {
  __shared__ float red[4];
  const int n = ((blockIdx.x & 7) << 10) | (blockIdx.x >> 3);  // bijective, 8192 blocks
  const int s = n & 2047;
  const int t = threadIdx.x;
  const int d0 = t * 4;
  const float* xr = x + (size_t)n * 1024;

  float xc[4], xm[4], xp[4];
  { float4 v = *(const float4*)(xr + d0); xc[0]=v.x; xc[1]=v.y; xc[2]=v.z; xc[3]=v.w; }
  if (s > 0) { float4 v = *(const float4*)(xr - 1024 + d0); xm[0]=v.x; xm[1]=v.y; xm[2]=v.z; xm[3]=v.w; }
  else { xm[0]=xm[1]=xm[2]=xm[3]=0.f; }
  if (s < 2047) { float4 v = *(const float4*)(xr + 1024 + d0); xp[0]=v.x; xp[1]=v.y; xp[2]=v.z; xp[3]=v.w; }
  else { xp[0]=xp[1]=xp[2]=xp[3]=0.f; }
  ushort4 gv = *(const ushort4*)(gab + (size_t)n * 1024 + d0);
  float ga4[4] = { b2f(gv.x), b2f(gv.y), b2f(gv.z), b2f(gv.w) };

  float y[4];
#pragma unroll
  for (int i = 0; i < 4; ++i) {
    int d = d0 + i;
    float lo = xm[i] * cw[d * 3] + xc[i] * cw[d * 3 + 1] + xp[i] * cw[d * 3 + 2] + cb[d];
    y[i] = xc[i] + ga4[i] + 0.3f * lo;
  }

  float sm = y[0] + y[1] + y[2] + y[3];
#pragma unroll
  for (int off = 32; off >= 1; off >>= 1) sm += __shfl_xor(sm, off, 64);
  if ((t & 63) == 0) red[t >> 6] = sm;
  __syncthreads();
  float mu = (red[0] + red[1] + red[2] + red[3]) * (1.f / 1024.f);
  __syncthreads();

  float vs = 0.f;
#pragma unroll
  for (int i = 0; i < 4; ++i) { float dd = y[i] - mu; vs += dd * dd; }
#pragma unroll
  for (int off = 32; off >= 1; off >>= 1) vs += __shfl_xor(vs, off, 64);
  if ((t & 63) == 0) red[t >> 6] = vs;
  __syncthreads();
  float var = (red[0] + red[1] + red[2] + red[3]) * (1.f / 1024.f);
  float rs = rsqrtf(var + 1e-5f);
#pragma unroll
  for (int i = 0; i < 4; ++i) {
    int d = d0 + i;
    out[(size_t)n * 1024 + d] = (y[i] - mu) * rs * lg[d] + lb[d];
  }
}

// ---------- launch ----------
extern "C" void kernel_launch(void* const* d_in, const int* in_sizes, int n_in,
                              void* d_out, int out_size, void* d_ws, size_t ws_size,
                              hipStream_t stream) {
  const float* x  = (const float*)d_in[0];
  const float* wq = (const float*)d_in[1];
  const float* bq = (const float*)d_in[2];
  const float* wk = (const float*)d_in[3];
  const float* bk = (const float*)d_in[4];
  const float* wv = (const float*)d_in[5];
  const float* bv = (const float*)d_in[6];
  const float* wo = (const float*)d_in[7];
  const float* bo = (const float*)d_in[8];
  const float* cw = (const float*)d_in[9];
  const float* cb = (const float*)d_in[10];
  const float* lg = (const float*)d_in[11];
  const float* lb = (const float*)d_in[12];
  float* out = (float*)d_out;

  char* ws = (char*)d_ws;
  const size_t MB = 1ull << 20;
  u16* xb  = (u16*)(ws + 0);        // 16MB; reused as ctx
  u16* wqb = (u16*)(ws + 16 * MB);  // wq|wk|wv|wo contiguous, 8MB
  u16* wvb = (u16*)(ws + 20 * MB);
  u16* wob = (u16*)(ws + 22 * MB);
  u16* qkb = (u16*)(ws + 24 * MB);  // 32MB [8192][2048]; reused as global_attn
  u16* vtb = (u16*)(ws + 56 * MB);  // 16MB V^T [1024 d][8192 tok]
  u16* ctx = xb;
  u16* gab = qkb;

  k_cvt_all<<<12288, 256, 0, stream>>>(x, wq, wk, wv, wo, xb, wqb);

  // fused [Q | K*c2] = X [wq|wk]^T : [8192][2048]
  k_gemm8<<<dim3(8, 32), 512, 0, stream>>>(xb, wqb, bq, bk, qkb, 8192, 2048, 1024);
  // V^T = Wv X^T (row-bias): [1024][8192]
  k_gemm_bt<1><<<dim3(64, 8), 256, 0, stream>>>(wvb, xb, bv, vtb, 1024, 8192, 1024);

  k_attn<<<dim3(64, 8), 256, 0, stream>>>(qkb, vtb, ctx);

  k_gemm_bt<0><<<dim3(8, 64), 256, 0, stream>>>(ctx, wob, bo, gab, 8192, 1024, 1024);

  k_epi<<<8192, 256, 0, stream>>>(x, gab, cw, cb, lg, lb, out);
}